// Round 4
// baseline (197.765 us; speedup 1.0000x reference)
//
#include <hip/hip_runtime.h>
#include <stdint.h>

#define C_CH 192
#define HW   4096
#define NB   16
#define NO   5
#define OUTSZ (NB * NO * C_CH * C_CH)   // 2,949,120 floats per chunk-copy

typedef __attribute__((ext_vector_type(8)))  short short8;
typedef __attribute__((ext_vector_type(16))) float floatx16;

__device__ __forceinline__ unsigned short f2bf(float f) {
    unsigned int u = __float_as_uint(f);
    unsigned int r = (u + 0x7fffu + ((u >> 16) & 1u)) >> 16;  // RNE to bf16
    return (unsigned short)r;
}

__device__ __forceinline__ uint4 s8u4(short8 f) { return *(uint4*)&f; }

// shift fragment toward lower index: out[j] = {ex, f[0..6]}   (dx = -1)
__device__ __forceinline__ short8 shift_m(short8 f, unsigned short ex) {
    uint4 v = *(uint4*)&f; uint4 w;
    w.x = (unsigned)ex   | (v.x << 16);
    w.y = (v.x >> 16)    | (v.y << 16);
    w.z = (v.y >> 16)    | (v.z << 16);
    w.w = (v.z >> 16)    | (v.w << 16);
    return *(short8*)&w;
}
// shift toward higher index: out[j] = {f[1..7], ex}   (dx = +1)
__device__ __forceinline__ short8 shift_p(short8 f, unsigned short ex) {
    uint4 v = *(uint4*)&f; uint4 w;
    w.x = (v.x >> 16) | (v.y << 16);
    w.y = (v.y >> 16) | (v.z << 16);
    w.z = (v.z >> 16) | (v.w << 16);
    w.w = (v.w >> 16) | ((unsigned)ex << 16);
    return *(short8*)&w;
}

// Build shifted variants of the 16-elem k-step fragment held as Uarr[S] across the
// lo=0/lo=1 half-waves. Edge elements come from the partner lane (lane^32) via shfl,
// with w=0 / w=63 clamps at S==0 (lo=0) and S==3 (lo=1).
#define MAKE_SHIFT(Uarr, S, Um, Up)                                              \
    do {                                                                         \
        uint4 _u0 = s8u4(Uarr[(S) > 0 ? (S) - 1 : 0]);                           \
        uint4 _u1 = s8u4(Uarr[S]);                                               \
        uint4 _u2 = s8u4(Uarr[(S) < 3 ? (S) + 1 : 3]);                           \
        unsigned _sm = lo ? _u0.w : _u1.w;                                       \
        unsigned _sp = lo ? _u1.x : _u2.x;                                       \
        unsigned _rm = (unsigned)__shfl_xor((int)_sm, 32, 64);                   \
        unsigned _rp = (unsigned)__shfl_xor((int)_sp, 32, 64);                   \
        unsigned short _exm = (unsigned short)(_rm >> 16);                       \
        if ((S) == 0) _exm = lo ? _exm : (unsigned short)(_u1.x & 0xffffu);      \
        unsigned short _exp = (unsigned short)(_rp & 0xffffu);                   \
        if ((S) == 3) _exp = lo ? (unsigned short)(_u1.w >> 16) : _exp;          \
        Um = shift_m(Uarr[S], _exm);                                             \
        Up = shift_p(Uarr[S], _exp);                                             \
    } while (0)

// ---------------- Kernel 1: fp32 -> bf16, fragment-tiled layout ----------------
// xb short index: ((b*6+cb)*512 + q)*256 + c'*8 + j   (cb = ch>>5, c' = ch&31, q = k>>3)
__global__ __launch_bounds__(256) void convert_kernel(const float* __restrict__ x,
                                                      unsigned short* __restrict__ xb,
                                                      float* __restrict__ norms) {
    if (blockIdx.x == 0 && threadIdx.x < NB * NO) norms[threadIdx.x] = 0.0f;
    int t   = blockIdx.x * 256 + threadIdx.x;   // 1,572,864 threads exactly
    int cq  = t >> 5;
    int cp  = t & 31;
    int bcb = cq >> 9;
    int q   = cq & 511;
    int b   = bcb / 6;
    int ch  = (bcb - b * 6) * 32 + cp;
    size_t fi = (size_t)(b * C_CH + ch) * HW + q * 8;
    const float4* p = (const float4*)(x + fi);
    float4 v0 = p[0], v1 = p[1];
    ushort4 o0, o1;
    o0.x = f2bf(v0.x); o0.y = f2bf(v0.y); o0.z = f2bf(v0.z); o0.w = f2bf(v0.w);
    o1.x = f2bf(v1.x); o1.y = f2bf(v1.y); o1.z = f2bf(v1.z); o1.w = f2bf(v1.w);
    ushort4* dst = (ushort4*)xb + (size_t)t * 2;
    dst[0] = o0; dst[1] = o1;
}

// ---------------- Kernel 2: fused 5-offset Gram, block-level K split ----------------
// RW = h-rows per wave. NC = 64/(4*RW) k-chunks across blocks.
// grid = NB * 36 * NC blocks; each block: 4 waves, wave wv covers rows
// [chunk*4*RW + wv*RW, +RW). Partials (one out-shaped copy per chunk) go to ws.
// dy=-1 terms re-indexed as sum_g A[g+1]*B[g] (g<63) + A[0]*B[0] boundary (h0==0).
template<int RW>
__global__ __launch_bounds__(256) void cofe_gemm(const unsigned short* __restrict__ xb,
                                                 float* __restrict__ part) {
    constexpr int NC  = 64 / (4 * RW);
    constexpr int TPB = NC * 36;               // works per batch
    int blk  = blockIdx.x;
    int work = (blk & 7) * ((NB * TPB) / 8) + (blk >> 3);   // XCD swizzle: 2 batches/XCD
    int b     = work / TPB;
    int r0    = work % TPB;
    int chunk = r0 / 36;
    int t     = r0 % 36;
    int cbA = t / 6, cbB = t % 6;
    int c0 = cbA * 32, d0 = cbB * 32;

    int wv   = threadIdx.x >> 6;
    int lane = threadIdx.x & 63;
    int lr   = lane & 31;
    int lo   = lane >> 5;
    int laneoff = lo * 32 + lr;                 // short8 units

    const short8* A8 = (const short8*)xb + (size_t)(b * 6 + cbA) * 16384;
    const short8* B8 = (const short8*)xb + (size_t)(b * 6 + cbB) * 16384;

    floatx16 acc[5];
    #pragma unroll
    for (int o = 0; o < 5; ++o)
        #pragma unroll
        for (int e = 0; e < 16; ++e)
            acc[o][e] = 0.0f;

    int h0 = chunk * (4 * RW) + wv * RW;

    short8 U[2][4];   // B rows: ping-pong
    short8 A[3][4];   // A rows: rotate (g, g+1, g+2)

    #pragma unroll
    for (int s = 0; s < 4; ++s) {
        U[0][s] = B8[(8 * h0 + 2 * s) * 32 + laneoff];
        A[0][s] = A8[(8 * h0 + 2 * s) * 32 + laneoff];
        A[1][s] = A8[(8 * (h0 + 1) + 2 * s) * 32 + laneoff];
    }

    // h = 0 boundary: dy=-1 offsets pair center row 0 with clamped side row 0
    if (h0 == 0) {
        #pragma unroll
        for (int s = 0; s < 4; ++s) {
            short8 Um, Up;
            MAKE_SHIFT(U[0], s, Um, Up);
            acc[0] = __builtin_amdgcn_mfma_f32_32x32x16_bf16(A[0][s], Um,      acc[0], 0, 0, 0);
            acc[1] = __builtin_amdgcn_mfma_f32_32x32x16_bf16(A[0][s], U[0][s], acc[1], 0, 0, 0);
            acc[2] = __builtin_amdgcn_mfma_f32_32x32x16_bf16(A[0][s], Up,      acc[2], 0, 0, 0);
        }
    }

    #pragma unroll
    for (int r = 0; r < RW; ++r) {
        int g  = h0 + r;
        const int cu = r & 1, nx = (r + 1) & 1;
        const int ia = r % 3, ib = (r + 1) % 3, ic = (r + 2) % 3;
        int ga = (g + 2 < 64) ? g + 2 : 63;     // A prefetch row (clamped dummy at tail)
        int gu = (g + 1 < 64) ? g + 1 : 63;     // B prefetch row
        #pragma unroll
        for (int s = 0; s < 4; ++s) {
            A[ic][s] = A8[(8 * ga + 2 * s) * 32 + laneoff];
            U[nx][s] = B8[(8 * gu + 2 * s) * 32 + laneoff];

            short8 Um, Up;
            MAKE_SHIFT(U[cu], s, Um, Up);

            // OFFSETS: 0:(-1,-1) 1:(-1,0) 2:(-1,1) 3:(0,-1) 4:(0,0)
            acc[4] = __builtin_amdgcn_mfma_f32_32x32x16_bf16(A[ia][s], U[cu][s], acc[4], 0, 0, 0);
            acc[3] = __builtin_amdgcn_mfma_f32_32x32x16_bf16(A[ia][s], Um,       acc[3], 0, 0, 0);
            if (r + 1 < RW || g < 63) {         // dy=-1 sum runs g = 0..62
                acc[1] = __builtin_amdgcn_mfma_f32_32x32x16_bf16(A[ib][s], U[cu][s], acc[1], 0, 0, 0);
                acc[0] = __builtin_amdgcn_mfma_f32_32x32x16_bf16(A[ib][s], Um,       acc[0], 0, 0, 0);
                acc[2] = __builtin_amdgcn_mfma_f32_32x32x16_bf16(A[ib][s], Up,       acc[2], 0, 0, 0);
            }
        }
    }

    // ---- epilogue: LDS-reduce 4 split-K wave partials, store chunk partial ----
    __shared__ float red[4096];   // 16 KB
    float4* red4 = (float4*)red;
    size_t pbase = ((size_t)chunk * (NB * NO) + b * NO) * (C_CH * C_CH);
    int tt = threadIdx.x;

    for (int o = 0; o < 5; ++o) {
        __syncthreads();
        #pragma unroll
        for (int reg = 0; reg < 16; ++reg) {
            int row = (reg & 3) + 8 * (reg >> 2) + 4 * lo;  // C/D layout (m74/m101)
            red[wv * 1024 + row * 32 + lr] = acc[o][reg];
        }
        __syncthreads();
        float4 s  = red4[tt];
        float4 s1 = red4[256 + tt];
        float4 s2 = red4[512 + tt];
        float4 s3 = red4[768 + tt];
        s.x += s1.x + s2.x + s3.x;
        s.y += s1.y + s2.y + s3.y;
        s.z += s1.z + s2.z + s3.z;
        s.w += s1.w + s2.w + s3.w;
        int row = tt >> 3;
        int col = (tt & 7) * 4;
        float* op = part + pbase + (size_t)o * (C_CH * C_CH)
                  + (size_t)(c0 + row) * C_CH + d0 + col;
        *(float4*)op = s;
    }
}

// ---------------- Kernel 3: sum chunk partials -> out, fused norm sumsq ----------------
__global__ __launch_bounds__(256) void reduce_kernel(const float* __restrict__ part,
                                                     float* __restrict__ out,
                                                     float* __restrict__ norms,
                                                     int nchunk) {
    int g  = blockIdx.x * 256 + threadIdx.x;    // float4 index, 737,280 total
    int bo = blockIdx.x / 36;                   // 9216 float4 per (b,o)
    float4 s = ((const float4*)part)[g];
    for (int c = 1; c < nchunk; ++c) {
        float4 v = ((const float4*)part)[(size_t)c * (OUTSZ / 4) + g];
        s.x += v.x; s.y += v.y; s.z += v.z; s.w += v.w;
    }
    ((float4*)out)[g] = s;
    float ss = s.x * s.x + s.y * s.y + s.z * s.z + s.w * s.w;
    #pragma unroll
    for (int off = 32; off; off >>= 1) ss += __shfl_down(ss, off, 64);
    if ((threadIdx.x & 63) == 0) atomicAdd(&norms[bo], ss);
}

// ---------------- Kernel 4: scale by 1/norm ----------------
__global__ __launch_bounds__(256) void scale_kernel(float* __restrict__ out,
                                                    const float* __restrict__ norms) {
    int g  = blockIdx.x * 256 + threadIdx.x;    // float4 index
    int bo = blockIdx.x / 36;
    float s = norms[bo];
    float inv = 1.0f / fmaxf(sqrtf(s), 1e-12f);
    float4 v = ((const float4*)out)[g];
    v.x *= inv; v.y *= inv; v.z *= inv; v.w *= inv;
    ((float4*)out)[g] = v;
}

extern "C" void kernel_launch(void* const* d_in, const int* in_sizes, int n_in,
                              void* d_out, int out_size, void* d_ws, size_t ws_size,
                              hipStream_t stream) {
    const float* x = (const float*)d_in[0];
    float* out = (float*)d_out;
    float* norms = (float*)d_ws;                                   // 80 floats (+pad)
    unsigned short* xb = (unsigned short*)((char*)d_ws + 512);     // 25,165,824 B bf16 tiled
    float* part = (float*)((char*)d_ws + 512 + 25165824);          // chunk partials

    const size_t chunk_bytes = (size_t)OUTSZ * 4;                  // 11,796,480 B
    const size_t base = 512 + 25165824;

    convert_kernel<<<6144, 256, 0, stream>>>(x, xb, norms);

    int nchunk;
    if (ws_size >= base + 4 * chunk_bytes) {
        nchunk = 4;
        cofe_gemm<4><<<NB * 36 * 4, 256, 0, stream>>>(xb, part);    // 2304 blocks
    } else if (ws_size >= base + 2 * chunk_bytes) {
        nchunk = 2;
        cofe_gemm<8><<<NB * 36 * 2, 256, 0, stream>>>(xb, part);    // 1152 blocks
    } else {
        nchunk = 1;
        cofe_gemm<16><<<NB * 36, 256, 0, stream>>>(xb, part);       // 576 blocks
    }

    reduce_kernel<<<2880, 256, 0, stream>>>(part, out, norms, nchunk);
    scale_kernel<<<2880, 256, 0, stream>>>(out, norms);
}

// Round 5
// 131.485 us; speedup vs baseline: 1.5041x; 1.5041x over previous
//
#include <hip/hip_runtime.h>
#include <stdint.h>

#define C_CH 192
#define HW   4096
#define NB   16
#define NO   5

typedef __attribute__((ext_vector_type(8)))  short short8;
typedef __attribute__((ext_vector_type(16))) float floatx16;

__device__ __forceinline__ unsigned short f2bf(float f) {
    unsigned int u = __float_as_uint(f);
    unsigned int r = (u + 0x7fffu + ((u >> 16) & 1u)) >> 16;  // RNE to bf16
    return (unsigned short)r;
}

__device__ __forceinline__ uint4 s8u4(short8 f) { return *(uint4*)&f; }

// shift fragment toward lower index: out[j] = {ex, f[0..6]}   (dx = -1)
__device__ __forceinline__ short8 shift_m(short8 f, unsigned short ex) {
    uint4 v = *(uint4*)&f; uint4 w;
    w.x = (unsigned)ex   | (v.x << 16);
    w.y = (v.x >> 16)    | (v.y << 16);
    w.z = (v.y >> 16)    | (v.z << 16);
    w.w = (v.z >> 16)    | (v.w << 16);
    return *(short8*)&w;
}
// shift toward higher index: out[j] = {f[1..7], ex}   (dx = +1)
__device__ __forceinline__ short8 shift_p(short8 f, unsigned short ex) {
    uint4 v = *(uint4*)&f; uint4 w;
    w.x = (v.x >> 16) | (v.y << 16);
    w.y = (v.y >> 16) | (v.z << 16);
    w.z = (v.z >> 16) | (v.w << 16);
    w.w = (v.w >> 16) | ((unsigned)ex << 16);
    return *(short8*)&w;
}

// Build shifted variants of the 16-elem k-step fragment held as Uarr[S] across the
// lo=0/lo=1 half-waves. Edge elements come from the partner lane (lane^32) via shfl,
// with w=0 / w=63 clamps at S==0 (lo=0) and S==3 (lo=1).
#define MAKE_SHIFT(Uarr, S, Um, Up)                                              \
    do {                                                                         \
        uint4 _u0 = s8u4(Uarr[(S) > 0 ? (S) - 1 : 0]);                           \
        uint4 _u1 = s8u4(Uarr[S]);                                               \
        uint4 _u2 = s8u4(Uarr[(S) < 3 ? (S) + 1 : 3]);                           \
        unsigned _sm = lo ? _u0.w : _u1.w;                                       \
        unsigned _sp = lo ? _u1.x : _u2.x;                                       \
        unsigned _rm = (unsigned)__shfl_xor((int)_sm, 32, 64);                   \
        unsigned _rp = (unsigned)__shfl_xor((int)_sp, 32, 64);                   \
        unsigned short _exm = (unsigned short)(_rm >> 16);                       \
        if ((S) == 0) _exm = lo ? _exm : (unsigned short)(_u1.x & 0xffffu);      \
        unsigned short _exp = (unsigned short)(_rp & 0xffffu);                   \
        if ((S) == 3) _exp = lo ? (unsigned short)(_u1.w >> 16) : _exp;          \
        Um = shift_m(Uarr[S], _exm);                                             \
        Up = shift_p(Uarr[S], _exp);                                             \
    } while (0)

// ---------------- Kernel 1: fp32 -> bf16, fragment-tiled layout ----------------
// xb short8 index: grp*16384 + q*32 + c'    (grp = b*6+cb, q = k>>3, c' = ch&31)
// Lane mapping: idx bits [13:8]=qhi [7:3]=c' [2:0]=qlo; q = qhi*8+qlo.
// Read: each 8-lane group reads 256 B contiguous of one channel row (full lines).
// Write: 4 lanes per 64-B line (full lines).
__global__ __launch_bounds__(256) void convert_kernel(const float* __restrict__ x,
                                                      unsigned short* __restrict__ xb,
                                                      float* __restrict__ norms) {
    if (blockIdx.x == 0 && threadIdx.x < NB * NO) norms[threadIdx.x] = 0.0f;
    int t   = blockIdx.x * 256 + threadIdx.x;   // 1,572,864 threads
    int grp = t >> 14;                          // 96 groups of (b, cb)
    int idx = t & 16383;
    int qhi = idx >> 8;
    int cp  = (idx >> 3) & 31;
    int qlo = idx & 7;
    int q   = qhi * 8 + qlo;
    int b   = grp / 6;
    int cb  = grp - b * 6;
    int ch  = cb * 32 + cp;
    const float4* p = (const float4*)(x + (size_t)(b * C_CH + ch) * HW + q * 8);
    float4 v0 = p[0], v1 = p[1];
    ushort4 o0, o1;
    o0.x = f2bf(v0.x); o0.y = f2bf(v0.y); o0.z = f2bf(v0.z); o0.w = f2bf(v0.w);
    o1.x = f2bf(v1.x); o1.y = f2bf(v1.y); o1.z = f2bf(v1.z); o1.w = f2bf(v1.w);
    ushort4* dst = (ushort4*)xb + ((size_t)grp * 16384 + q * 32 + cp) * 2;
    dst[0] = o0; dst[1] = o1;
}

// ---------------- Kernel 2: fused 5-offset Gram, full K, 8-wave split ----------------
// grid 576 = 16 b x 36 (32x32)-tiles; 512 threads = 8 waves; wave wv covers h-rows
// [8wv, 8wv+8). Epilogue reduces 8 wave-partials in 32 KB LDS, stores out, and does
// ONE norm atomic per (block, offset) -> 2880 atomics total (R4's 11,520 atomics on
// 5 cache lines were the 72-us reduce_kernel).
// dy=-1 terms re-indexed: sum_g A[g+1]*B[g] (g=0..62) + A[0]*B[0] boundary (wave 0).
__global__ __launch_bounds__(512) void cofe_gemm(const unsigned short* __restrict__ xb,
                                                 float* __restrict__ out,
                                                 float* __restrict__ norms) {
    constexpr int RW = 8;
    int blk  = blockIdx.x;
    int work = (blk & 7) * 72 + (blk >> 3);     // XCD swizzle: 2 batches per XCD
    int b = work / 36;
    int t = work % 36;
    int cbA = t / 6, cbB = t % 6;
    int c0 = cbA * 32, d0 = cbB * 32;

    int wv   = threadIdx.x >> 6;                // 0..7
    int lane = threadIdx.x & 63;
    int lr   = lane & 31;
    int lo   = lane >> 5;
    int laneoff = lo * 32 + lr;                 // short8 units

    const short8* A8 = (const short8*)xb + (size_t)(b * 6 + cbA) * 16384;
    const short8* B8 = (const short8*)xb + (size_t)(b * 6 + cbB) * 16384;

    floatx16 acc[5];
    #pragma unroll
    for (int o = 0; o < 5; ++o)
        #pragma unroll
        for (int e = 0; e < 16; ++e)
            acc[o][e] = 0.0f;

    int h0 = wv * RW;

    short8 U[2][4];   // B rows: ping-pong
    short8 A[3][4];   // A rows: rotate (g, g+1, g+2)

    #pragma unroll
    for (int s = 0; s < 4; ++s) {
        U[0][s] = B8[(8 * h0 + 2 * s) * 32 + laneoff];
        A[0][s] = A8[(8 * h0 + 2 * s) * 32 + laneoff];
        A[1][s] = A8[(8 * (h0 + 1) + 2 * s) * 32 + laneoff];
    }

    // h = 0 boundary: dy=-1 offsets pair center row 0 with clamped side row 0
    if (h0 == 0) {
        #pragma unroll
        for (int s = 0; s < 4; ++s) {
            short8 Um, Up;
            MAKE_SHIFT(U[0], s, Um, Up);
            acc[0] = __builtin_amdgcn_mfma_f32_32x32x16_bf16(A[0][s], Um,      acc[0], 0, 0, 0);
            acc[1] = __builtin_amdgcn_mfma_f32_32x32x16_bf16(A[0][s], U[0][s], acc[1], 0, 0, 0);
            acc[2] = __builtin_amdgcn_mfma_f32_32x32x16_bf16(A[0][s], Up,      acc[2], 0, 0, 0);
        }
    }

    #pragma unroll
    for (int r = 0; r < RW; ++r) {
        int g  = h0 + r;
        const int cu = r & 1, nx = (r + 1) & 1;
        const int ia = r % 3, ib = (r + 1) % 3, ic = (r + 2) % 3;
        int ga = (g + 2 < 64) ? g + 2 : 63;     // A prefetch row (clamped dummy at tail)
        int gu = (g + 1 < 64) ? g + 1 : 63;     // B prefetch row
        #pragma unroll
        for (int s = 0; s < 4; ++s) {
            A[ic][s] = A8[(8 * ga + 2 * s) * 32 + laneoff];
            U[nx][s] = B8[(8 * gu + 2 * s) * 32 + laneoff];

            short8 Um, Up;
            MAKE_SHIFT(U[cu], s, Um, Up);

            // OFFSETS: 0:(-1,-1) 1:(-1,0) 2:(-1,1) 3:(0,-1) 4:(0,0)
            acc[4] = __builtin_amdgcn_mfma_f32_32x32x16_bf16(A[ia][s], U[cu][s], acc[4], 0, 0, 0);
            acc[3] = __builtin_amdgcn_mfma_f32_32x32x16_bf16(A[ia][s], Um,       acc[3], 0, 0, 0);
            if (r + 1 < RW || g < 63) {         // dy=-1 sum runs g = 0..62
                acc[1] = __builtin_amdgcn_mfma_f32_32x32x16_bf16(A[ib][s], U[cu][s], acc[1], 0, 0, 0);
                acc[0] = __builtin_amdgcn_mfma_f32_32x32x16_bf16(A[ib][s], Um,       acc[0], 0, 0, 0);
                acc[2] = __builtin_amdgcn_mfma_f32_32x32x16_bf16(A[ib][s], Up,       acc[2], 0, 0, 0);
            }
        }
    }

    // ---- epilogue: LDS-reduce 8 wave partials, store, one norm atomic per offset ----
    __shared__ float red[8192];   // 32 KB
    __shared__ float wsum[4];
    float4* red4 = (float4*)red;
    size_t obase = (size_t)b * NO * (C_CH * C_CH);
    int tt = threadIdx.x;

    for (int o = 0; o < 5; ++o) {
        __syncthreads();
        #pragma unroll
        for (int reg = 0; reg < 16; ++reg) {
            int row = (reg & 3) + 8 * (reg >> 2) + 4 * lo;  // C/D layout (m74/m101)
            red[wv * 1024 + row * 32 + lr] = acc[o][reg];
        }
        __syncthreads();
        if (tt < 256) {
            float4 s = red4[tt];
            #pragma unroll
            for (int seg = 1; seg < 8; ++seg) {
                float4 v = red4[seg * 256 + tt];
                s.x += v.x; s.y += v.y; s.z += v.z; s.w += v.w;
            }
            int row = tt >> 3;
            int col = (tt & 7) * 4;
            float* op = out + obase + (size_t)o * (C_CH * C_CH)
                      + (size_t)(c0 + row) * C_CH + d0 + col;
            *(float4*)op = s;

            float ss = s.x * s.x + s.y * s.y + s.z * s.z + s.w * s.w;
            #pragma unroll
            for (int off = 32; off; off >>= 1) ss += __shfl_down(ss, off, 64);
            if (lane == 0) wsum[tt >> 6] = ss;
        }
        __syncthreads();
        if (tt == 0) atomicAdd(&norms[b * NO + o], wsum[0] + wsum[1] + wsum[2] + wsum[3]);
    }
}

// ---------------- Kernel 3: scale by 1/norm ----------------
__global__ __launch_bounds__(256) void scale_kernel(float* __restrict__ out,
                                                    const float* __restrict__ norms) {
    int g  = blockIdx.x * 256 + threadIdx.x;    // float4 index, 737,280 total
    int bo = blockIdx.x / 36;                   // 9216 float4 per (b,o)
    float s = norms[bo];
    float inv = 1.0f / fmaxf(sqrtf(s), 1e-12f);
    float4 v = ((const float4*)out)[g];
    v.x *= inv; v.y *= inv; v.z *= inv; v.w *= inv;
    ((float4*)out)[g] = v;
}

extern "C" void kernel_launch(void* const* d_in, const int* in_sizes, int n_in,
                              void* d_out, int out_size, void* d_ws, size_t ws_size,
                              hipStream_t stream) {
    const float* x = (const float*)d_in[0];
    float* out = (float*)d_out;
    float* norms = (float*)d_ws;                                   // 80 floats (+pad)
    unsigned short* xb = (unsigned short*)((char*)d_ws + 512);     // 25,165,824 B bf16 tiled

    convert_kernel<<<6144, 256, 0, stream>>>(x, xb, norms);
    cofe_gemm<<<576, 512, 0, stream>>>(xb, out, norms);
    scale_kernel<<<2880, 256, 0, stream>>>(out, norms);
}